// Round 1
// baseline (319.138 us; speedup 1.0000x reference)
//
#include <hip/hip_runtime.h>

// Problem constants from setup_inputs(): B=32, N=1024, D=512, T=4096.
#define B_ 32
#define N_ 1024
#define D_ 512
#define T_ 4096
#define D4_ (D_ / 4)   // 128 float4 per frame

// Kernel 1: per-batch inclusive scan of durations + interval scatter of
// source indices into idxmap[B*T], plus mask output.
// One block per batch, N threads (one per phoneme).
__global__ __launch_bounds__(N_) void lr_scan_kernel(
    const int* __restrict__ dur,
    int* __restrict__ idxmap,
    float* __restrict__ mask_out)
{
    __shared__ int s[N_];
    const int b = blockIdx.x;
    const int tid = threadIdx.x;

    s[tid] = dur[b * N_ + tid];
    __syncthreads();

    // Hillis-Steele inclusive scan (10 steps for N=1024).
    for (int off = 1; off < N_; off <<= 1) {
        int add = (tid >= off) ? s[tid - off] : 0;
        __syncthreads();
        s[tid] += add;
        __syncthreads();
    }

    const int end   = s[tid];
    const int start = (tid == 0) ? 0 : s[tid - 1];
    const int total = s[N_ - 1];

    // Frames [start, end) belong to phoneme tid (clamped to T).
    const int cs = min(start, T_);
    const int ce = min(end,   T_);
    for (int t = cs; t < ce; ++t) {
        idxmap[b * T_ + t] = tid;
    }

    // Tail frames t >= total: masked out -> sentinel -1 (gather writes zeros).
    for (int t = total + tid; t < T_; t += N_) {
        idxmap[b * T_ + t] = -1;
    }

    // Mask output (bool as 0.0/1.0 float).
    for (int t = tid; t < T_; t += N_) {
        mask_out[b * T_ + t] = (t < total) ? 1.0f : 0.0f;
    }
}

// Kernel 2: gather x rows into the expanded output, float4-vectorized,
// grid-stride over all B*T*D4 float4 elements.
__global__ __launch_bounds__(256) void lr_gather_kernel(
    const float4* __restrict__ x,
    const int* __restrict__ idxmap,
    float4* __restrict__ out)
{
    const int total4 = B_ * T_ * D4_;            // 16,777,216 (< 2^31)
    const int stride = gridDim.x * blockDim.x;
    for (int gid = blockIdx.x * blockDim.x + threadIdx.x;
         gid < total4; gid += stride) {
        const int frame = gid >> 7;              // / D4_ (=128)
        const int d4    = gid & (D4_ - 1);
        const int idx   = idxmap[frame];         // broadcast across 128 lanes
        float4 val;
        if (idx >= 0) {
            const int b = frame >> 12;           // / T_ (=4096)
            val = x[(b * N_ + idx) * D4_ + d4];
        } else {
            val = make_float4(0.f, 0.f, 0.f, 0.f);
        }
        out[gid] = val;
    }
}

extern "C" void kernel_launch(void* const* d_in, const int* in_sizes, int n_in,
                              void* d_out, int out_size, void* d_ws, size_t ws_size,
                              hipStream_t stream) {
    const float* x   = (const float*)d_in[0];
    const int*   dur = (const int*)d_in[1];
    // d_in[2] is target_len (=4096), known at compile time.

    float* out      = (float*)d_out;
    float* mask_out = out + (size_t)B_ * T_ * D_;  // mask follows expanded
    int*   idxmap   = (int*)d_ws;                  // B*T ints = 512 KiB

    lr_scan_kernel<<<B_, N_, 0, stream>>>(dur, idxmap, mask_out);
    lr_gather_kernel<<<2048, 256, 0, stream>>>((const float4*)x, idxmap,
                                               (float4*)out);
}

// Round 2
// 312.670 us; speedup vs baseline: 1.0207x; 1.0207x over previous
//
#include <hip/hip_runtime.h>

// Problem constants from setup_inputs(): B=32, N=1024, D=512, T=4096.
#define B_ 32
#define N_ 1024
#define D_ 512
#define T_ 4096
#define D4_ (D_ / 4)   // 128 float4 per frame

// Kernel 1: per-batch inclusive scan of durations + interval scatter of
// source indices into idxmap[B*T], plus mask output.
// One block per batch, N threads (one per phoneme).
__global__ __launch_bounds__(N_) void lr_scan_kernel(
    const int* __restrict__ dur,
    int* __restrict__ idxmap,
    float* __restrict__ mask_out)
{
    __shared__ int s[N_];
    const int b = blockIdx.x;
    const int tid = threadIdx.x;

    s[tid] = dur[b * N_ + tid];
    __syncthreads();

    // Hillis-Steele inclusive scan (10 steps for N=1024).
    for (int off = 1; off < N_; off <<= 1) {
        int add = (tid >= off) ? s[tid - off] : 0;
        __syncthreads();
        s[tid] += add;
        __syncthreads();
    }

    const int end   = s[tid];
    const int start = (tid == 0) ? 0 : s[tid - 1];
    const int total = s[N_ - 1];

    // Frames [start, end) belong to phoneme tid (clamped to T).
    const int cs = min(start, T_);
    const int ce = min(end,   T_);
    for (int t = cs; t < ce; ++t) {
        idxmap[b * T_ + t] = tid;
    }

    // Tail frames t >= total: sentinel -1 (gather writes zeros there).
    for (int t = total + tid; t < T_; t += N_) {
        idxmap[b * T_ + t] = -1;
    }

    // Mask output (bool as 0.0/1.0 float).
    for (int t = tid; t < T_; t += N_) {
        mask_out[b * T_ + t] = (t < total) ? 1.0f : 0.0f;
    }
}

// Kernel 2: gather x rows into the expanded output.
// Exact grid: 16384 blocks x 256 threads, each thread does 4 independent
// float4 gathers (ILP). frame = gid>>7 is wave-uniform (a 64-lane span of
// consecutive gids never crosses a 128-float4 frame boundary), so the idx
// is hoisted to SGPR via readfirstlane. Streaming out-writes are
// nontemporal to keep L2 for the reused x rows.
__global__ __launch_bounds__(256) void lr_gather_kernel(
    const float4* __restrict__ x,
    const int* __restrict__ idxmap,
    float4* __restrict__ out)
{
    const int base = blockIdx.x * 1024 + threadIdx.x;  // 1024 float4 per block
#pragma unroll
    for (int k = 0; k < 4; ++k) {
        const int gid   = base + k * 256;
        const int frame = gid >> 7;                    // wave-uniform
        const int idx   = __builtin_amdgcn_readfirstlane(idxmap[frame]);
        float4 val = make_float4(0.f, 0.f, 0.f, 0.f);
        if (idx >= 0) {
            const int b = frame >> 12;                 // frame / T_
            val = x[(b * N_ + idx) * D4_ + (gid & (D4_ - 1))];
        }
        __builtin_nontemporal_store(val.x, &out[gid].x);
        __builtin_nontemporal_store(val.y, &out[gid].y);
        __builtin_nontemporal_store(val.z, &out[gid].z);
        __builtin_nontemporal_store(val.w, &out[gid].w);
    }
}

extern "C" void kernel_launch(void* const* d_in, const int* in_sizes, int n_in,
                              void* d_out, int out_size, void* d_ws, size_t ws_size,
                              hipStream_t stream) {
    const float* x   = (const float*)d_in[0];
    const int*   dur = (const int*)d_in[1];
    // d_in[2] is target_len (=4096), known at compile time.

    float* out      = (float*)d_out;
    float* mask_out = out + (size_t)B_ * T_ * D_;  // mask follows expanded
    int*   idxmap   = (int*)d_ws;                  // B*T ints = 512 KiB

    lr_scan_kernel<<<B_, N_, 0, stream>>>(dur, idxmap, mask_out);

    const int total4 = B_ * T_ * D4_;              // 16,777,216
    lr_gather_kernel<<<total4 / 1024, 256, 0, stream>>>(
        (const float4*)x, idxmap, (float4*)out);
}